// Round 3
// baseline (654.279 us; speedup 1.0000x reference)
//
#include <hip/hip_runtime.h>

#define D 64
#define EPS 1e-12f
#define WPITCH 68   // LDS row pitch in floats: 68*4B=272B, 16B-aligned, breaks pow2 banks
#define BSHIFT 7    // bucket width = 128 nodes
#define BW 128
#define NBMAX 2048  // LDS histogram capacity in bhist (N up to 262144)

typedef unsigned short u16;

__device__ __forceinline__ float bf2f(u16 u) {
    return __uint_as_float(((unsigned)u) << 16);
}
// round-to-nearest-even f32 -> bf16 (finite values)
__device__ __forceinline__ u16 f2bf(float f) {
    unsigned u = __float_as_uint(f);
    u += 0x7fffu + ((u >> 16) & 1u);
    return (u16)(u >> 16);
}
__device__ __forceinline__ float loadf(const void* p, size_t i, int bf) {
    return bf ? bf2f(((const u16*)p)[i]) : ((const float*)p)[i];
}

#define FMA4(acc, s, v)                       \
    do {                                      \
        acc.x = fmaf((s), (v).x, acc.x);      \
        acc.y = fmaf((s), (v).y, acc.y);      \
        acc.z = fmaf((s), (v).z, acc.z);      \
        acc.w = fmaf((s), (v).w, acc.w);      \
    } while (0)

// Detect input dtype: bf16 N(0,1) data never has exponent >= 0xC0; f32 data
// read as u16 halves triggers constantly. flag=1 -> bf16, flag=0 -> f32.
__global__ __launch_bounds__(64) void detect_kernel(const u16* __restrict__ x,
                                                    int* __restrict__ flag) {
    int lane = threadIdx.x;
    int bad = 0;
    for (int i = 0; i < 64; ++i) {
        u16 u = x[lane * 64 + i];
        int e = (u >> 7) & 0xFF;
        if (e >= 0xC0) bad = 1;
    }
    unsigned long long b = __ballot(bad);
    if (lane == 0) *flag = (b == 0ull) ? 1 : 0;
}

// ---- bucketed CSR build (once per launch; shared by both layers) ----
// Old single-level fill did 1.2M random 4B stores -> 83MB of 64B-line
// write-allocate HBM traffic (94us). Two-level version keeps all scatter
// writes inside 782 sequential regions (bfill) or a ~6KB L2-hot window
// per block (csr_from_buckets).

__global__ __launch_bounds__(256) void zero_kernel(int* __restrict__ a, int n) {
    int i = blockIdx.x * blockDim.x + threadIdx.x;
    if (i < n) a[i] = 0;
}

// bucket histogram: LDS-privatized per block, then one flush per bucket.
__global__ __launch_bounds__(256) void bhist_kernel(const int* __restrict__ dst,
                                                    int* __restrict__ bcounts,
                                                    int E, int NB) {
    __shared__ int lh[NBMAX];
    int t = threadIdx.x;
    if (NB <= NBMAX) {
        for (int i = t; i < NB; i += 256) lh[i] = 0;
        __syncthreads();
        for (int e = blockIdx.x * 256 + t; e < E; e += gridDim.x * 256)
            atomicAdd(&lh[dst[e] >> BSHIFT], 1);
        __syncthreads();
        for (int i = t; i < NB; i += 256)
            if (lh[i]) atomicAdd(&bcounts[i], lh[i]);
    } else {  // generic fallback
        for (int e = blockIdx.x * 256 + t; e < E; e += gridDim.x * 256)
            atomicAdd(&bcounts[dst[e] >> BSHIFT], 1);
    }
}

// exclusive scan over NB bucket counts (single wave); also inits bcursor.
__global__ __launch_bounds__(64) void bscan_kernel(const int* __restrict__ bcounts,
                                                   int* __restrict__ boffsets,
                                                   int* __restrict__ bcursor, int NB) {
    int l = threadIdx.x;
    int total = 0;
    for (int base = 0; base < NB; base += 64) {
        int v = (base + l < NB) ? bcounts[base + l] : 0;
        int inc = v;
        for (int d = 1; d < 64; d <<= 1) {
            int u = __shfl_up(inc, d);
            if (l >= d) inc += u;
        }
        int excl = inc - v + total;
        if (base + l < NB) { boffsets[base + l] = excl; bcursor[base + l] = excl; }
        total += __shfl(inc, 63);
    }
}

// append (src,dst) to the dst's bucket region. Cursor guarantees sequential
// positions within each bucket -> 8B writes coalesce into full 64B lines in L2.
__global__ __launch_bounds__(256) void bfill_kernel(const int* __restrict__ src,
                                                    const int* __restrict__ dst,
                                                    int* __restrict__ bcursor,
                                                    int2* __restrict__ bucket, int E) {
    int e = blockIdx.x * blockDim.x + threadIdx.x;
    if (e >= E) return;
    int s = src[e], d = dst[e];
    int p = atomicAdd(&bcursor[d >> BSHIFT], 1);
    bucket[p] = make_int2(s, d);
}

// one block per bucket: local node histogram + scan -> counts/offsets
// (coalesced), then scatter src into this bucket's contiguous sorted_src
// window via LDS cursors. No capacity limits anywhere.
__global__ __launch_bounds__(256) void csr_from_buckets_kernel(
    const int2* __restrict__ bucket,
    const int* __restrict__ bcounts, const int* __restrict__ boffsets,
    int* __restrict__ counts, int* __restrict__ offsets,
    int* __restrict__ sorted_src, int N)
{
    __shared__ int hist[BW];
    __shared__ int cur[BW];
    __shared__ int wt[4];

    const int b = blockIdx.x;
    const int t = threadIdx.x;
    const int nbase = b << BSHIFT;
    const int ecnt = bcounts[b];
    const int ebase = boffsets[b];

    if (t < BW) hist[t] = 0;
    __syncthreads();

    for (int e = t; e < ecnt; e += 256)
        atomicAdd(&hist[bucket[ebase + e].y - nbase], 1);
    __syncthreads();

    // exclusive scan of hist[0..127] using waves 0 and 1
    int v = (t < BW) ? hist[t] : 0;
    int inc = v;
    for (int d = 1; d < 64; d <<= 1) {
        int u = __shfl_up(inc, d);
        if ((t & 63) >= d) inc += u;
    }
    if ((t & 63) == 63) wt[t >> 6] = inc;
    __syncthreads();
    if (t < BW) {
        int excl = inc - v + ((t >= 64) ? wt[0] : 0);
        cur[t] = excl;
        int node = nbase + t;
        if (node < N) {
            counts[node] = v;
            offsets[node] = ebase + excl;
        }
    }
    __syncthreads();

    for (int e = t; e < ecnt; e += 256) {
        int2 p = bucket[ebase + e];
        int pos = atomicAdd(&cur[p.y - nbase], 1);
        sorted_src[ebase + pos] = p.x;
    }
}

// ---- per-layer kernels (unchanged from R2) ----

// Kernel A: per-node L2 norm; store norm and 1/max(norm,eps).
__global__ __launch_bounds__(256) void norm_init_kernel(
    const void* __restrict__ xin, float* __restrict__ nx, float* __restrict__ rnx,
    int N, const int* __restrict__ flagp)
{
    const int bf = *flagp;
    int node = (int)((blockIdx.x * blockDim.x + threadIdx.x) >> 6);
    int lane = threadIdx.x & 63;
    if (node >= N) return;
    float v = loadf(xin, (size_t)node * D + lane, bf);
    float s = v * v;
    s += __shfl_xor(s, 32); s += __shfl_xor(s, 16); s += __shfl_xor(s, 8);
    s += __shfl_xor(s, 4);  s += __shfl_xor(s, 2);  s += __shfl_xor(s, 1);
    if (lane == 0) {
        float n = sqrtf(s);
        nx[node] = n;
        rnx[node] = 1.0f / fmaxf(n, EPS);
    }
}

// Kernel B: pull-mode aggregation via CSR, one wave per node, lane = feature.
// Batched 8-wide (then 4-wide) so 8 row-loads + 8 rnx loads are in flight.
__global__ __launch_bounds__(256) void gather_kernel(
    const int* __restrict__ offsets, const int* __restrict__ counts,
    const int* __restrict__ sorted_src,
    const void* __restrict__ xin, const float* __restrict__ rnx,
    float* __restrict__ agg, int N, const int* __restrict__ flagp)
{
    const int bf = *flagp;
    int node = (int)((blockIdx.x * blockDim.x + threadIdx.x) >> 6);
    int lane = threadIdx.x & 63;
    if (node >= N) return;

    float acc = loadf(xin, (size_t)node * D + lane, bf) * rnx[node];  // self term

    int start = offsets[node];
    int deg = counts[node];
    for (int i = 0; i < deg; i += 64) {
        int cnt = min(deg - i, 64);
        int id = (lane < cnt) ? sorted_src[start + i + lane] : 0;
        int j = 0;
        for (; j + 8 <= cnt; j += 8) {
            float v[8], wv[8];
#pragma unroll
            for (int jj = 0; jj < 8; ++jj) {
                int s = __shfl(id, j + jj);
                wv[jj] = rnx[s];
                v[jj] = loadf(xin, (size_t)s * D + lane, bf);
            }
#pragma unroll
            for (int jj = 0; jj < 8; ++jj) acc = fmaf(v[jj], wv[jj], acc);
        }
        if (j + 4 <= cnt) {
            float v[4], wv[4];
#pragma unroll
            for (int jj = 0; jj < 4; ++jj) {
                int s = __shfl(id, j + jj);
                wv[jj] = rnx[s];
                v[jj] = loadf(xin, (size_t)s * D + lane, bf);
            }
#pragma unroll
            for (int jj = 0; jj < 4; ++jj) acc = fmaf(v[jj], wv[jj], acc);
            j += 4;
        }
        for (; j < cnt; ++j) {
            int s = __shfl(id, j);
            acc = fmaf(loadf(xin, (size_t)s * D + lane, bf), rnx[s], acc);
        }
    }
    agg[(size_t)node * D + lane] = acc;
}

// Kernel C: msg-norm + two 64x64 GEMVs + final l2norm (+optional relu).
// Register blocking: lane = (sub, cg); each lane computes 4 nodes x 4 cols.
#define KSTEP(kk, comp)                                                     \
    {                                                                       \
        float4 a = *((const float4*)(wlp + (kk) * WPITCH));                 \
        float4 b = *((const float4*)(wrp + (kk) * WPITCH));                 \
        FMA4(acc[0], m[0].comp, a); FMA4(acc[0], xf[0].comp, b);            \
        FMA4(acc[1], m[1].comp, a); FMA4(acc[1], xf[1].comp, b);            \
        FMA4(acc[2], m[2].comp, a); FMA4(acc[2], xf[2].comp, b);            \
        FMA4(acc[3], m[3].comp, a); FMA4(acc[3], xf[3].comp, b);            \
    }

__global__ __launch_bounds__(256) void epilogue_kernel(
    const float* __restrict__ agg, const float* __restrict__ nx,
    const void* __restrict__ xin,
    const void* __restrict__ wl, const void* __restrict__ bl,
    const void* __restrict__ wr, const void* __restrict__ scale_p,
    void* __restrict__ out, int N, const int* __restrict__ flagp, int relu)
{
    __shared__ float lds_wl[D * WPITCH];   // [k*WPITCH + j] = Wl[j][k]
    __shared__ float lds_wr[D * WPITCH];
    __shared__ float lds_bl[D];
    __shared__ float msgbuf[4][16 * WPITCH];  // [wave][row*WPITCH + k]

    const int bf = *flagp;
    const int t = threadIdx.x;
    for (int idx = t; idx < D * D; idx += 256) {
        int j = idx >> 6, k = idx & 63;
        lds_wl[k * WPITCH + j] = loadf(wl, idx, bf);
        lds_wr[k * WPITCH + j] = loadf(wr, idx, bf);
    }
    if (t < D) lds_bl[t] = loadf(bl, t, bf);
    __syncthreads();

    const float scl = loadf(scale_p, 0, bf);
    const int w = t >> 6, lane = t & 63;
    const int sub = lane >> 4, cg = lane & 15;

    const int node0 = blockIdx.x * 64 + w * 16 + sub * 4;
    int n[4];
    bool valid[4];
    float4 a4[4];
    float nxv[4];
#pragma unroll
    for (int r = 0; r < 4; ++r) {
        int nn = node0 + r;
        valid[r] = nn < N;
        n[r] = valid[r] ? nn : N - 1;
        a4[r] = ((const float4*)(agg + (size_t)n[r] * D))[cg];
        nxv[r] = nx[n[r]];
    }

    float* mrow = msgbuf[w];
#pragma unroll
    for (int r = 0; r < 4; ++r) {
        float4 v4 = a4[r];
        float s = v4.x * v4.x + v4.y * v4.y + v4.z * v4.z + v4.w * v4.w;
        s += __shfl_xor(s, 1); s += __shfl_xor(s, 2);
        s += __shfl_xor(s, 4); s += __shfl_xor(s, 8);
        float minv = scl * nxv[r] / fmaxf(sqrtf(s), EPS);
        *((float4*)(mrow + (sub * 4 + r) * WPITCH + cg * 4)) =
            make_float4(v4.x * minv, v4.y * minv, v4.z * minv, v4.w * minv);
    }
    // no barrier: producer/consumer lanes are in the same wave (in-order LDS)

    float4 acc[4];
    {
        float4 b4 = ((const float4*)lds_bl)[cg];
#pragma unroll
        for (int r = 0; r < 4; ++r) acc[r] = b4;
    }

    const float* wlbase = lds_wl + cg * 4;
    const float* wrbase = lds_wr + cg * 4;

    if (bf) {
#pragma unroll
        for (int k4 = 0; k4 < 16; ++k4) {
            float4 m[4], xf[4];
#pragma unroll
            for (int r = 0; r < 4; ++r) {
                m[r] = *((const float4*)(mrow + (sub * 4 + r) * WPITCH + k4 * 4));
                ushort4 xu = ((const ushort4*)((const u16*)xin + (size_t)n[r] * D))[k4];
                xf[r] = make_float4(bf2f(xu.x), bf2f(xu.y), bf2f(xu.z), bf2f(xu.w));
            }
            const float* wlp = wlbase + (k4 * 4) * WPITCH;
            const float* wrp = wrbase + (k4 * 4) * WPITCH;
            KSTEP(0, x) KSTEP(1, y) KSTEP(2, z) KSTEP(3, w)
        }
    } else {
#pragma unroll
        for (int k4 = 0; k4 < 16; ++k4) {
            float4 m[4], xf[4];
#pragma unroll
            for (int r = 0; r < 4; ++r) {
                m[r] = *((const float4*)(mrow + (sub * 4 + r) * WPITCH + k4 * 4));
                xf[r] = ((const float4*)((const float*)xin + (size_t)n[r] * D))[k4];
            }
            const float* wlp = wlbase + (k4 * 4) * WPITCH;
            const float* wrp = wrbase + (k4 * 4) * WPITCH;
            KSTEP(0, x) KSTEP(1, y) KSTEP(2, z) KSTEP(3, w)
        }
    }

#pragma unroll
    for (int r = 0; r < 4; ++r) {
        float4 v = acc[r];
        float s2 = v.x * v.x + v.y * v.y + v.z * v.z + v.w * v.w;
        s2 += __shfl_xor(s2, 1); s2 += __shfl_xor(s2, 2);
        s2 += __shfl_xor(s2, 4); s2 += __shfl_xor(s2, 8);
        float inv = 1.0f / fmaxf(sqrtf(s2), EPS);
        float4 rv = make_float4(v.x * inv, v.y * inv, v.z * inv, v.w * inv);
        if (relu) {
            rv.x = fmaxf(rv.x, 0.f); rv.y = fmaxf(rv.y, 0.f);
            rv.z = fmaxf(rv.z, 0.f); rv.w = fmaxf(rv.w, 0.f);
        }
        if (valid[r]) {
            if (bf) {
                ushort4 o = make_ushort4(f2bf(rv.x), f2bf(rv.y), f2bf(rv.z), f2bf(rv.w));
                ((ushort4*)((u16*)out + (size_t)n[r] * D))[cg] = o;
            } else {
                ((float4*)((float*)out + (size_t)n[r] * D))[cg] = rv;
            }
        }
    }
}

extern "C" void kernel_launch(void* const* d_in, const int* in_sizes, int n_in,
                              void* d_out, int out_size, void* d_ws, size_t ws_size,
                              hipStream_t stream)
{
    const void* x   = d_in[0];
    const void* Wl0 = d_in[1];
    const void* bl0 = d_in[2];
    const void* Wr0 = d_in[3];
    const void* sc0 = d_in[4];
    const void* Wl1 = d_in[5];
    const void* bl1 = d_in[6];
    const void* Wr1 = d_in[7];
    const void* sc1 = d_in[8];
    const int* ei   = (const int*)d_in[9];

    const int N = in_sizes[0] / D;
    const int E = in_sizes[9] / 2;
    const int* src = ei;
    const int* dst = ei + E;

    const int NB = (N + BW - 1) >> BSHIFT;  // buckets of 128 nodes

    // workspace (~37.5 MB):
    //   agg f32 (N*D) | nx f32 (N) | rnx f32 (N) | flag int |
    //   counts int (N) | offsets int (N) |
    //   bcounts int (NB) | boffsets int (NB) | bcursor int (NB) |
    //   [8B align] bucket int2 (E) | sorted_src int (E)
    float* agg       = (float*)d_ws;
    float* nx        = agg + (size_t)N * D;
    float* rnx       = nx + N;
    int* flag        = (int*)(rnx + N);
    int* counts      = flag + 1;
    int* offsets     = counts + N;
    int* bcounts     = offsets + N;
    int* boffsets    = bcounts + NB;
    int* bcursor     = boffsets + NB;
    char* pal        = (char*)(bcursor + NB);
    pal += ((size_t)16 - ((size_t)pal & 15)) & 15;   // 16B align
    int2* bucket     = (int2*)pal;
    int* sorted_src  = (int*)(bucket + E);

    // inter-layer h lives in d_out (layer-1 epilogue reads only its own rows
    // of h before overwriting them; all cross-node h reads happen earlier).
    void* h = d_out;

    dim3 blk(256);
    int gridE  = (E + 255) / 256;   // 1 thread/edge
    int gridA  = (N + 3) / 4;       // 1 wave/node
    int gridC  = (N + 63) / 64;     // epilogue: 64 nodes/block

    detect_kernel<<<1, 64, 0, stream>>>((const u16*)x, flag);

    // ---- bucketed CSR build (edge structure shared by both layers) ----
    zero_kernel<<<(NB + 255) / 256, blk, 0, stream>>>(bcounts, NB);
    bhist_kernel<<<256, blk, 0, stream>>>(dst, bcounts, E, NB);
    bscan_kernel<<<1, 64, 0, stream>>>(bcounts, boffsets, bcursor, NB);
    bfill_kernel<<<gridE, blk, 0, stream>>>(src, dst, bcursor, bucket, E);
    csr_from_buckets_kernel<<<NB, blk, 0, stream>>>(bucket, bcounts, boffsets,
                                                    counts, offsets, sorted_src, N);

    // ---- layer 0 (input x, output h -> d_out, relu) ----
    norm_init_kernel<<<gridA, blk, 0, stream>>>(x, nx, rnx, N, flag);
    gather_kernel<<<gridA, blk, 0, stream>>>(offsets, counts, sorted_src, x, rnx,
                                             agg, N, flag);
    epilogue_kernel<<<gridC, blk, 0, stream>>>(agg, nx, x, Wl0, bl0, Wr0, sc0,
                                               h, N, flag, 1);

    // ---- layer 1 (input h = d_out, output d_out, no relu) ----
    norm_init_kernel<<<gridA, blk, 0, stream>>>(h, nx, rnx, N, flag);
    gather_kernel<<<gridA, blk, 0, stream>>>(offsets, counts, sorted_src, h, rnx,
                                             agg, N, flag);
    epilogue_kernel<<<gridC, blk, 0, stream>>>(agg, nx, h, Wl1, bl1, Wr1, sc1,
                                               d_out, N, flag, 0);
}

// Round 4
// 368.074 us; speedup vs baseline: 1.7776x; 1.7776x over previous
//
#include <hip/hip_runtime.h>

#define D 64
#define EPS 1e-12f
#define WPITCH 68   // LDS row pitch in floats: 272B, breaks pow2 bank aliasing
#define BSHIFT 8    // bucket width = 256 nodes
#define BW 256
#define NBMAX 2048  // LDS capacity for per-block bucket arrays (N up to 524288)
#define NBLK 256    // partition blocks

typedef unsigned short u16;

__device__ __forceinline__ float bf2f(u16 u) {
    return __uint_as_float(((unsigned)u) << 16);
}
// round-to-nearest-even f32 -> bf16 (finite values)
__device__ __forceinline__ u16 f2bf(float f) {
    unsigned u = __float_as_uint(f);
    u += 0x7fffu + ((u >> 16) & 1u);
    return (u16)(u >> 16);
}
__device__ __forceinline__ float loadf(const void* p, size_t i, int bf) {
    return bf ? bf2f(((const u16*)p)[i]) : ((const float*)p)[i];
}

#define FMA4(acc, s, v)                       \
    do {                                      \
        acc.x = fmaf((s), (v).x, acc.x);      \
        acc.y = fmaf((s), (v).y, acc.y);      \
        acc.z = fmaf((s), (v).z, acc.z);      \
        acc.w = fmaf((s), (v).w, acc.w);      \
    } while (0)

// Detect input dtype: bf16 N(0,1) data never has exponent >= 0xC0; f32 data
// read as u16 halves triggers constantly. flag=1 -> bf16, flag=0 -> f32.
__global__ __launch_bounds__(64) void detect_kernel(const u16* __restrict__ x,
                                                    int* __restrict__ flag) {
    int lane = threadIdx.x;
    int bad = 0;
    for (int i = 0; i < 64; ++i) {
        u16 u = x[lane * 64 + i];
        int e = (u >> 7) & 0xFF;
        if (e >= 0xC0) bad = 1;
    }
    unsigned long long b = __ballot(bad);
    if (lane == 0) *flag = (b == 0ull) ? 1 : 0;
}

// ---- two-pass bucketed CSR build (zero global atomics in the hot path) ----
// R3 lesson: 1.2M global atomicAdds on 782 cursors serialized ~1536-deep
// (284us, VALUBusy 0.1%). Now: per-block LDS histograms -> exclusive scan of
// the (bucket, block) matrix -> replay with LDS-only cursors, every write
// lands at a precomputed position in a per-(block,bucket) contiguous chunk.

__global__ __launch_bounds__(256) void zero_kernel(int* __restrict__ a, int n) {
    int i = blockIdx.x * blockDim.x + threadIdx.x;
    if (i < n) a[i] = 0;
}

// pass A: per-block bucket histogram over this block's contiguous edge chunk.
// blockhist layout bucket-major: blockhist[i*NBLK + b].
__global__ __launch_bounds__(256) void bhist_kernel(const int* __restrict__ dst,
                                                    int* __restrict__ blockhist,
                                                    int E, int NB) {
    __shared__ int lh[NBMAX];
    const int b = blockIdx.x, t = threadIdx.x;
    const int per = (E + NBLK - 1) / NBLK;
    const int e0 = b * per, e1 = min(E, e0 + per);
    if (NB <= NBMAX) {
        for (int i = t; i < NB; i += 256) lh[i] = 0;
        __syncthreads();
        for (int e = e0 + t; e < e1; e += 256)
            atomicAdd(&lh[dst[e] >> BSHIFT], 1);
        __syncthreads();
        for (int i = t; i < NB; i += 256) blockhist[i * NBLK + b] = lh[i];
    } else {  // generic fallback (blockhist pre-zeroed by host-side branch)
        for (int e = e0 + t; e < e1; e += 256)
            atomicAdd(&blockhist[(dst[e] >> BSHIFT) * NBLK + b], 1);
    }
}

// scanA: per-1024-chunk partial sums of a[M]
__global__ __launch_bounds__(256) void scanA_kernel(const int* __restrict__ a,
                                                    int* __restrict__ partials, int M) {
    int b = blockIdx.x, t = threadIdx.x;
    int base = b * 1024 + t * 4;
    int s = 0;
#pragma unroll
    for (int i = 0; i < 4; ++i) {
        int idx = base + i;
        if (idx < M) s += a[idx];
    }
    s += __shfl_xor(s, 32); s += __shfl_xor(s, 16); s += __shfl_xor(s, 8);
    s += __shfl_xor(s, 4);  s += __shfl_xor(s, 2);  s += __shfl_xor(s, 1);
    __shared__ int wt[4];
    if ((t & 63) == 0) wt[t >> 6] = s;
    __syncthreads();
    if (t == 0) partials[b] = wt[0] + wt[1] + wt[2] + wt[3];
}

// scanB: exclusive scan of partials (single wave)
__global__ __launch_bounds__(64) void scanB_kernel(int* __restrict__ partials, int NP) {
    int l = threadIdx.x;
    int total = 0;
    for (int base = 0; base < NP; base += 64) {
        int v = (base + l < NP) ? partials[base + l] : 0;
        int inc = v;
        for (int d = 1; d < 64; d <<= 1) {
            int u = __shfl_up(inc, d);
            if (l >= d) inc += u;
        }
        if (base + l < NP) partials[base + l] = inc - v + total;
        total += __shfl(inc, 63);
    }
}

// scanC: per-element exclusive positions
__global__ __launch_bounds__(256) void scanC_kernel(const int* __restrict__ a,
                                                    const int* __restrict__ partials,
                                                    int* __restrict__ pos, int M) {
    int b = blockIdx.x, t = threadIdx.x;
    int base = b * 1024 + t * 4;
    int v[4];
    int s = 0;
#pragma unroll
    for (int i = 0; i < 4; ++i) {
        int idx = base + i;
        v[i] = (idx < M) ? a[idx] : 0;
        s += v[i];
    }
    int li = t & 63, w = t >> 6;
    int inc = s;
    for (int d = 1; d < 64; d <<= 1) {
        int u = __shfl_up(inc, d);
        if (li >= d) inc += u;
    }
    __shared__ int wt[4];
    if (li == 63) wt[w] = inc;
    __syncthreads();
    int woff = 0;
    for (int i = 0; i < w; ++i) woff += wt[i];
    int run = partials[b] + woff + (inc - s);
#pragma unroll
    for (int i = 0; i < 4; ++i) {
        int idx = base + i;
        if (idx < M) { pos[idx] = run; run += v[i]; }
    }
}

// bucket meta from scanned positions: boffsets[i] = pos[i*NBLK]; counts by diff.
__global__ __launch_bounds__(256) void bmeta_kernel(const int* __restrict__ pos,
                                                    int* __restrict__ bcounts,
                                                    int* __restrict__ boffsets,
                                                    int NB, int E) {
    int i = blockIdx.x * blockDim.x + threadIdx.x;
    if (i < NB) {
        int s = pos[(size_t)i * NBLK];
        boffsets[i] = s;
        int nxt = (i + 1 < NB) ? pos[(size_t)(i + 1) * NBLK] : E;
        bcounts[i] = nxt - s;
    }
}

// pass C: replay this block's edge chunk; LDS cursors seeded from pos give
// exact, contention-free destinations. Packed entry: (src<<8)|dst_local
// (requires N < 2^24; here N=100000 < 2^17).
__global__ __launch_bounds__(256) void bfill_kernel(const int* __restrict__ src,
                                                    const int* __restrict__ dst,
                                                    int* __restrict__ pos,
                                                    int* __restrict__ bucket,
                                                    int E, int NB) {
    __shared__ int cur[NBMAX];
    const int b = blockIdx.x, t = threadIdx.x;
    const int per = (E + NBLK - 1) / NBLK;
    const int e0 = b * per, e1 = min(E, e0 + per);
    if (NB <= NBMAX) {
        for (int i = t; i < NB; i += 256) cur[i] = pos[(size_t)i * NBLK + b];
        __syncthreads();
        for (int e = e0 + t; e < e1; e += 256) {
            int s = src[e], d = dst[e];
            int p = atomicAdd(&cur[d >> BSHIFT], 1);
            bucket[p] = (s << BSHIFT) | (d & (BW - 1));
        }
    } else {  // fallback: bmeta already ran, pos is free to consume
        for (int e = e0 + t; e < e1; e += 256) {
            int s = src[e], d = dst[e];
            int p = atomicAdd(&pos[(size_t)(d >> BSHIFT) * NBLK + b], 1);
            bucket[p] = (s << BSHIFT) | (d & (BW - 1));
        }
    }
}

// one block per bucket (256 nodes): LDS node histogram + scan -> counts/offsets
// (coalesced), then scatter src into this bucket's contiguous sorted_src
// window (L2-hot) via LDS cursors.
__global__ __launch_bounds__(256) void csr_from_buckets_kernel(
    const int* __restrict__ bucket,
    const int* __restrict__ bcounts, const int* __restrict__ boffsets,
    int* __restrict__ counts, int* __restrict__ offsets,
    int* __restrict__ sorted_src, int N)
{
    __shared__ int hist[BW];
    __shared__ int cur[BW];
    __shared__ int wt[4];

    const int b = blockIdx.x;
    const int t = threadIdx.x;
    const int nbase = b << BSHIFT;
    const int ecnt = bcounts[b];
    const int ebase = boffsets[b];

    hist[t] = 0;
    __syncthreads();

    for (int e = t; e < ecnt; e += 256)
        atomicAdd(&hist[bucket[ebase + e] & (BW - 1)], 1);
    __syncthreads();

    // exclusive scan of hist[0..255] across 4 waves
    int v = hist[t];
    int inc = v;
    for (int d = 1; d < 64; d <<= 1) {
        int u = __shfl_up(inc, d);
        if ((t & 63) >= d) inc += u;
    }
    if ((t & 63) == 63) wt[t >> 6] = inc;
    __syncthreads();
    int woff = 0;
    for (int i = 0; i < (t >> 6); ++i) woff += wt[i];
    int excl = inc - v + woff;
    cur[t] = excl;
    int node = nbase + t;
    if (node < N) {
        counts[node] = v;
        offsets[node] = ebase + excl;
    }
    __syncthreads();

    for (int e = t; e < ecnt; e += 256) {
        int pv = bucket[ebase + e];
        int p = atomicAdd(&cur[pv & (BW - 1)], 1);
        sorted_src[ebase + p] = ((unsigned)pv) >> BSHIFT;
    }
}

// ---- per-layer kernels ----

// Kernel A: per-node L2 norm; store norm and 1/max(norm,eps).
__global__ __launch_bounds__(256) void norm_init_kernel(
    const void* __restrict__ xin, float* __restrict__ nx, float* __restrict__ rnx,
    int N, const int* __restrict__ flagp)
{
    const int bf = *flagp;
    int node = (int)((blockIdx.x * blockDim.x + threadIdx.x) >> 6);
    int lane = threadIdx.x & 63;
    if (node >= N) return;
    float v = loadf(xin, (size_t)node * D + lane, bf);
    float s = v * v;
    s += __shfl_xor(s, 32); s += __shfl_xor(s, 16); s += __shfl_xor(s, 8);
    s += __shfl_xor(s, 4);  s += __shfl_xor(s, 2);  s += __shfl_xor(s, 1);
    if (lane == 0) {
        float n = sqrtf(s);
        nx[node] = n;
        rnx[node] = 1.0f / fmaxf(n, EPS);
    }
}

// Kernel B v2: pull-mode aggregation, one wave per node.
// 16 lanes x float4 per row; the wave's 4 lane-groups process 4 edges
// concurrently, unrolled x2 (8 rows in flight). 4x fewer load instructions
// than the per-lane-scalar version; cross-group combine = 2 shfl_xor at end.
__device__ __forceinline__ float4 loadrow4(const void* p, int row, int lane16, int bf) {
    if (bf) {
        ushort4 u = ((const ushort4*)((const u16*)p + (size_t)row * D))[lane16];
        return make_float4(bf2f(u.x), bf2f(u.y), bf2f(u.z), bf2f(u.w));
    }
    return ((const float4*)((const float*)p + (size_t)row * D))[lane16];
}

__global__ __launch_bounds__(256) void gather_kernel(
    const int* __restrict__ offsets, const int* __restrict__ counts,
    const int* __restrict__ sorted_src,
    const void* __restrict__ xin, const float* __restrict__ rnx,
    float* __restrict__ agg, int N, const int* __restrict__ flagp)
{
    const int bf = *flagp;
    int node = (int)((blockIdx.x * blockDim.x + threadIdx.x) >> 6);
    int lane = threadIdx.x & 63;
    if (node >= N) return;
    const int lane16 = lane & 15, grp = lane >> 4;

    float4 acc = make_float4(0.f, 0.f, 0.f, 0.f);
    if (grp == 0) {  // self term, group 0 only
        float4 xs = loadrow4(xin, node, lane16, bf);
        FMA4(acc, rnx[node], xs);
    }

    const int start = offsets[node];
    const int deg = counts[node];
    for (int i = 0; i < deg; i += 64) {
        int cnt = min(deg - i, 64);
        int id = (lane < cnt) ? sorted_src[start + i + lane] : 0;
        int j = 0;
        for (; j + 8 <= cnt; j += 8) {
            int s0 = __shfl(id, j + grp);
            int s1 = __shfl(id, j + 4 + grp);
            float w0 = rnx[s0], w1 = rnx[s1];
            float4 v0 = loadrow4(xin, s0, lane16, bf);
            float4 v1 = loadrow4(xin, s1, lane16, bf);
            FMA4(acc, w0, v0);
            FMA4(acc, w1, v1);
        }
        if (j + 4 <= cnt) {
            int s0 = __shfl(id, j + grp);
            float w0 = rnx[s0];
            float4 v0 = loadrow4(xin, s0, lane16, bf);
            FMA4(acc, w0, v0);
            j += 4;
        }
        if (j < cnt) {  // 1-3 leftover edges
            int e = j + grp;
            int s0 = __shfl(id, min(e, cnt - 1));
            if (e < cnt) {
                float w0 = rnx[s0];
                float4 v0 = loadrow4(xin, s0, lane16, bf);
                FMA4(acc, w0, v0);
            }
        }
    }

    // combine the 4 lane-groups
    acc.x += __shfl_xor(acc.x, 16); acc.y += __shfl_xor(acc.y, 16);
    acc.z += __shfl_xor(acc.z, 16); acc.w += __shfl_xor(acc.w, 16);
    acc.x += __shfl_xor(acc.x, 32); acc.y += __shfl_xor(acc.y, 32);
    acc.z += __shfl_xor(acc.z, 32); acc.w += __shfl_xor(acc.w, 32);
    if (grp == 0)
        ((float4*)(agg + (size_t)node * D))[lane16] = acc;
}

// Kernel C: msg-norm + two 64x64 GEMVs + final l2norm (+optional relu).
// Register blocking: lane = (sub, cg); each lane computes 4 nodes x 4 cols.
#define KSTEP(kk, comp)                                                     \
    {                                                                       \
        float4 a = *((const float4*)(wlp + (kk) * WPITCH));                 \
        float4 b = *((const float4*)(wrp + (kk) * WPITCH));                 \
        FMA4(acc[0], m[0].comp, a); FMA4(acc[0], xf[0].comp, b);            \
        FMA4(acc[1], m[1].comp, a); FMA4(acc[1], xf[1].comp, b);            \
        FMA4(acc[2], m[2].comp, a); FMA4(acc[2], xf[2].comp, b);            \
        FMA4(acc[3], m[3].comp, a); FMA4(acc[3], xf[3].comp, b);            \
    }

__global__ __launch_bounds__(256) void epilogue_kernel(
    const float* __restrict__ agg, const float* __restrict__ nx,
    const void* __restrict__ xin,
    const void* __restrict__ wl, const void* __restrict__ bl,
    const void* __restrict__ wr, const void* __restrict__ scale_p,
    void* __restrict__ out, int N, const int* __restrict__ flagp, int relu)
{
    __shared__ float lds_wl[D * WPITCH];   // [k*WPITCH + j] = Wl[j][k]
    __shared__ float lds_wr[D * WPITCH];
    __shared__ float lds_bl[D];
    __shared__ float msgbuf[4][16 * WPITCH];  // [wave][row*WPITCH + k]

    const int bf = *flagp;
    const int t = threadIdx.x;
    for (int idx = t; idx < D * D; idx += 256) {
        int j = idx >> 6, k = idx & 63;
        lds_wl[k * WPITCH + j] = loadf(wl, idx, bf);
        lds_wr[k * WPITCH + j] = loadf(wr, idx, bf);
    }
    if (t < D) lds_bl[t] = loadf(bl, t, bf);
    __syncthreads();

    const float scl = loadf(scale_p, 0, bf);
    const int w = t >> 6, lane = t & 63;
    const int sub = lane >> 4, cg = lane & 15;

    const int node0 = blockIdx.x * 64 + w * 16 + sub * 4;
    int n[4];
    bool valid[4];
    float4 a4[4];
    float nxv[4];
#pragma unroll
    for (int r = 0; r < 4; ++r) {
        int nn = node0 + r;
        valid[r] = nn < N;
        n[r] = valid[r] ? nn : N - 1;
        a4[r] = ((const float4*)(agg + (size_t)n[r] * D))[cg];
        nxv[r] = nx[n[r]];
    }

    float* mrow = msgbuf[w];
#pragma unroll
    for (int r = 0; r < 4; ++r) {
        float4 v4 = a4[r];
        float s = v4.x * v4.x + v4.y * v4.y + v4.z * v4.z + v4.w * v4.w;
        s += __shfl_xor(s, 1); s += __shfl_xor(s, 2);
        s += __shfl_xor(s, 4); s += __shfl_xor(s, 8);
        float minv = scl * nxv[r] / fmaxf(sqrtf(s), EPS);
        *((float4*)(mrow + (sub * 4 + r) * WPITCH + cg * 4)) =
            make_float4(v4.x * minv, v4.y * minv, v4.z * minv, v4.w * minv);
    }
    // no barrier: producer/consumer lanes are in the same wave (in-order LDS)

    float4 acc[4];
    {
        float4 b4 = ((const float4*)lds_bl)[cg];
#pragma unroll
        for (int r = 0; r < 4; ++r) acc[r] = b4;
    }

    const float* wlbase = lds_wl + cg * 4;
    const float* wrbase = lds_wr + cg * 4;

    if (bf) {
#pragma unroll
        for (int k4 = 0; k4 < 16; ++k4) {
            float4 m[4], xf[4];
#pragma unroll
            for (int r = 0; r < 4; ++r) {
                m[r] = *((const float4*)(mrow + (sub * 4 + r) * WPITCH + k4 * 4));
                ushort4 xu = ((const ushort4*)((const u16*)xin + (size_t)n[r] * D))[k4];
                xf[r] = make_float4(bf2f(xu.x), bf2f(xu.y), bf2f(xu.z), bf2f(xu.w));
            }
            const float* wlp = wlbase + (k4 * 4) * WPITCH;
            const float* wrp = wrbase + (k4 * 4) * WPITCH;
            KSTEP(0, x) KSTEP(1, y) KSTEP(2, z) KSTEP(3, w)
        }
    } else {
#pragma unroll
        for (int k4 = 0; k4 < 16; ++k4) {
            float4 m[4], xf[4];
#pragma unroll
            for (int r = 0; r < 4; ++r) {
                m[r] = *((const float4*)(mrow + (sub * 4 + r) * WPITCH + k4 * 4));
                xf[r] = ((const float4*)((const float*)xin + (size_t)n[r] * D))[k4];
            }
            const float* wlp = wlbase + (k4 * 4) * WPITCH;
            const float* wrp = wrbase + (k4 * 4) * WPITCH;
            KSTEP(0, x) KSTEP(1, y) KSTEP(2, z) KSTEP(3, w)
        }
    }

#pragma unroll
    for (int r = 0; r < 4; ++r) {
        float4 v = acc[r];
        float s2 = v.x * v.x + v.y * v.y + v.z * v.z + v.w * v.w;
        s2 += __shfl_xor(s2, 1); s2 += __shfl_xor(s2, 2);
        s2 += __shfl_xor(s2, 4); s2 += __shfl_xor(s2, 8);
        float inv = 1.0f / fmaxf(sqrtf(s2), EPS);
        float4 rv = make_float4(v.x * inv, v.y * inv, v.z * inv, v.w * inv);
        if (relu) {
            rv.x = fmaxf(rv.x, 0.f); rv.y = fmaxf(rv.y, 0.f);
            rv.z = fmaxf(rv.z, 0.f); rv.w = fmaxf(rv.w, 0.f);
        }
        if (valid[r]) {
            if (bf) {
                ushort4 o = make_ushort4(f2bf(rv.x), f2bf(rv.y), f2bf(rv.z), f2bf(rv.w));
                ((ushort4*)((u16*)out + (size_t)n[r] * D))[cg] = o;
            } else {
                ((float4*)((float*)out + (size_t)n[r] * D))[cg] = rv;
            }
        }
    }
}

extern "C" void kernel_launch(void* const* d_in, const int* in_sizes, int n_in,
                              void* d_out, int out_size, void* d_ws, size_t ws_size,
                              hipStream_t stream)
{
    const void* x   = d_in[0];
    const void* Wl0 = d_in[1];
    const void* bl0 = d_in[2];
    const void* Wr0 = d_in[3];
    const void* sc0 = d_in[4];
    const void* Wl1 = d_in[5];
    const void* bl1 = d_in[6];
    const void* Wr1 = d_in[7];
    const void* sc1 = d_in[8];
    const int* ei   = (const int*)d_in[9];

    const int N = in_sizes[0] / D;
    const int E = in_sizes[9] / 2;
    const int* src = ei;
    const int* dst = ei + E;

    const int NB = (N + BW - 1) >> BSHIFT;   // buckets of 256 nodes
    const int M  = NB * NBLK;                // (bucket, block) matrix
    const int NP = (M + 1023) / 1024;        // scan partials

    // workspace (~38.5 MB):
    //   agg f32 (N*D) | nx f32 (N) | rnx f32 (N) | flag int |
    //   counts int (N) | offsets int (N) | bcounts int (NB) | boffsets int (NB) |
    //   blockhist int (M) | pos int (M) | partials int (NP) |
    //   bucket int (E, packed) | sorted_src int (E)
    float* agg       = (float*)d_ws;
    float* nx        = agg + (size_t)N * D;
    float* rnx       = nx + N;
    int* flag        = (int*)(rnx + N);
    int* counts      = flag + 1;
    int* offsets     = counts + N;
    int* bcounts     = offsets + N;
    int* boffsets    = bcounts + NB;
    int* blockhist   = boffsets + NB;
    int* pos         = blockhist + M;
    int* partials    = pos + M;
    int* bucket      = partials + NP;
    int* sorted_src  = bucket + E;

    // inter-layer h lives in d_out (layer-1 epilogue reads only its own rows
    // of h before overwriting them; all cross-node h reads happen earlier).
    void* h = d_out;

    dim3 blk(256);
    int gridA  = (N + 3) / 4;       // 1 wave/node
    int gridC  = (N + 63) / 64;     // epilogue: 64 nodes/block

    detect_kernel<<<1, 64, 0, stream>>>((const u16*)x, flag);

    // ---- two-pass bucketed CSR build (shared by both layers) ----
    if (NB > NBMAX)  // fallback path accumulates atomically; needs zeroed hist
        zero_kernel<<<(M + 255) / 256, blk, 0, stream>>>(blockhist, M);
    bhist_kernel<<<NBLK, blk, 0, stream>>>(dst, blockhist, E, NB);
    scanA_kernel<<<NP, blk, 0, stream>>>(blockhist, partials, M);
    scanB_kernel<<<1, 64, 0, stream>>>(partials, NP);
    scanC_kernel<<<NP, blk, 0, stream>>>(blockhist, partials, pos, M);
    bmeta_kernel<<<(NB + 255) / 256, blk, 0, stream>>>(pos, bcounts, boffsets, NB, E);
    bfill_kernel<<<NBLK, blk, 0, stream>>>(src, dst, pos, bucket, E, NB);
    csr_from_buckets_kernel<<<NB, blk, 0, stream>>>(bucket, bcounts, boffsets,
                                                    counts, offsets, sorted_src, N);

    // ---- layer 0 (input x, output h -> d_out, relu) ----
    norm_init_kernel<<<gridA, blk, 0, stream>>>(x, nx, rnx, N, flag);
    gather_kernel<<<gridA, blk, 0, stream>>>(offsets, counts, sorted_src, x, rnx,
                                             agg, N, flag);
    epilogue_kernel<<<gridC, blk, 0, stream>>>(agg, nx, x, Wl0, bl0, Wr0, sc0,
                                               h, N, flag, 1);

    // ---- layer 1 (input h = d_out, output d_out, no relu) ----
    norm_init_kernel<<<gridA, blk, 0, stream>>>(h, nx, rnx, N, flag);
    gather_kernel<<<gridA, blk, 0, stream>>>(offsets, counts, sorted_src, h, rnx,
                                             agg, N, flag);
    epilogue_kernel<<<gridC, blk, 0, stream>>>(agg, nx, h, Wl1, bl1, Wr1, sc1,
                                               d_out, N, flag, 0);
}